// Round 14
// baseline (49.843 us; speedup 1.0000x reference)
//
#include <hip/hip_runtime.h>
#include <hip/hip_fp16.h>

#define BATCH 8192
#define IN_F 128
#define OUT_F 256
#define LC 23        // grid_size + order
#define BROW 768     // bytes per (j,g) cp2 row: 16 cols x 24 slots x 2B
#define JPW 16       // j's per wave (8-way in-block K-split)

typedef _Float16 f16x8 __attribute__((ext_vector_type(8)));
typedef float f32x4 __attribute__((ext_vector_type(4)));
typedef _Float16 half2v __attribute__((ext_vector_type(2)));

// ===========================================================================
// prep_fast (R13-verified): coalesced repack coeffs -> cp2.
// Row (j,g) = [q 3][col 16][16B], slot>=20 -> 0.
// ===========================================================================
__global__ __launch_bounds__(256) void prep_fast(
    const float* __restrict__ coeffs, char* __restrict__ cp2) {
    __shared__ float slab[256 * LC];   // 23552 B
    const size_t base = (size_t)blockIdx.x * 256;   // first (i,j) pair
    {
        const float4* g4 = reinterpret_cast<const float4*>(coeffs + base * LC);
        float4* s4 = reinterpret_cast<float4*>(slab);
        for (int it = threadIdx.x; it < (256 * LC) / 4; it += 256)
            s4[it] = g4[it];
    }
    __syncthreads();
    const int t = (int)base + threadIdx.x;   // pair index = i*128 + j
    const int i = t >> 7;
    const int j = t & 127;
    const float* my = slab + threadIdx.x * LC;
    const int g = i >> 4;
    const int col = i & 15;
    char* row = cp2 + (size_t)(j * 16 + g) * BROW + col * 16;
    f16x8 w0, w1, w2;
#pragma unroll
    for (int e = 0; e < 8; ++e) {
        w0[e] = (_Float16)my[e];
        w1[e] = (_Float16)my[8 + e];
        w2[e] = (e < 4) ? (_Float16)my[16 + e] : (_Float16)0.0f;
    }
    *reinterpret_cast<f16x8*>(row) = w0;
    *reinterpret_cast<f16x8*>(row + 256) = w1;
    *reinterpret_cast<f16x8*>(row + 512) = w2;
}

// ===========================================================================
// kan_mfma8 (R8/R13-verified, UNCHANGED — the real output path)
// ===========================================================================
__global__ __launch_bounds__(512, 4) void kan_mfma8(
    const float* __restrict__ x, const char* __restrict__ cp2,
    float* __restrict__ out) {
    __shared__ uint2 mlds[IN_F][64];   // 64 KiB: [j][row] meta

    const int tid = threadIdx.x;
    const int lane = tid & 63;
    const int ks = tid >> 6;
    const int l15 = lane & 15;
    const int q = lane >> 4;
    const int q4 = q * 4;
    const int qc = (q < 3) ? q : 2;

    int wg = (blockIdx.x & 7) * 64 + (blockIdx.x >> 3);
    const int mb = wg >> 2;
    const int bn = wg & 3;
    const int b0 = mb * 64;

    {
        const int row = lane;
        const int jb = ks * 16;
        const float4* xr = reinterpret_cast<const float4*>(
            x + (size_t)(b0 + row) * IN_F + jb);
#pragma unroll
        for (int u = 0; u < 4; ++u) {
            float4 xv = xr[u];
#pragma unroll
            for (int e = 0; e < 4; ++e) {
                float xvv = (e == 0) ? xv.x : (e == 1) ? xv.y
                           : (e == 2) ? xv.z : xv.w;
                float s = 1.0f / (1.0f + __expf(-xvv));
                float idxf = s * 19.0f;
                int k = (int)idxf;
                k = (k > 18) ? 18 : k;
                float w1 = idxf - (float)k;
                float w0 = 1.0f - w1;
                unsigned u0 = __half_as_ushort(__float2half(w0));
                unsigned u1 = __half_as_ushort(__float2half(w1));
                unsigned lo, hi;
                if (k & 1) { lo = u0 << 16; hi = u1; }
                else       { lo = u0 | (u1 << 16); hi = 0u; }
                unsigned P = (unsigned)(k >> 1);
                mlds[jb + u * 4 + e][row] = uint2{lo, hi | (P << 16)};
            }
        }
    }
    __syncthreads();

    const int j0 = ks * JPW;
    const char* bbase = cp2 + (size_t)(bn * 4) * BROW + qc * 256 + l15 * 16;
    auto bld = [&](int j, int nf) {
        return *reinterpret_cast<const f16x8*>(
            bbase + (size_t)(j * 16 + nf) * BROW);
    };

    f32x4 acc[4][4];
#pragma unroll
    for (int mf = 0; mf < 4; ++mf)
#pragma unroll
        for (int nf = 0; nf < 4; ++nf) acc[mf][nf] = f32x4{0.f, 0.f, 0.f, 0.f};

    f16x8 rc[4], rn[4];
#pragma unroll
    for (int h = 0; h < 4; ++h) rc[h] = bld(j0, h);

    auto step = [&](f16x8 (&cur)[4], f16x8 (&nxt)[4], int j, int jn) {
#pragma unroll
        for (int h = 0; h < 4; ++h) nxt[h] = bld(jn, h);
#pragma unroll
        for (int mf = 0; mf < 4; ++mf) {
            uint2 m = mlds[j][mf * 16 + l15];
            unsigned lo = m.x;
            unsigned hi = m.y & 0xFFFFu;
            int d = (int)(m.y >> 16) - q4;
            union { uint32_t u[4]; f16x8 h; } au;
#pragma unroll
            for (int r = 0; r < 4; ++r) {
                uint32_t v = (d == r) ? lo : 0u;
                v = (d == r - 1) ? hi : v;
                au.u[r] = v;
            }
#pragma unroll
            for (int nf = 0; nf < 4; ++nf)
                acc[mf][nf] = __builtin_amdgcn_mfma_f32_16x16x32_f16(
                    au.h, cur[nf], acc[mf][nf], 0, 0, 0);
        }
    };

    for (int jj = 0; jj < JPW; jj += 2) {
        step(rc, rn, j0 + jj, j0 + jj + 1);
        step(rn, rc, j0 + jj + 1, j0 + ((jj + 2) & (JPW - 1)));
    }

    __syncthreads();
    float* red = reinterpret_cast<float*>(&mlds[0][0]);
#pragma unroll
    for (int p = 0; p < 2; ++p) {
        if (p) __syncthreads();
#pragma unroll
        for (int mf = 0; mf < 4; ++mf)
#pragma unroll
            for (int t = 0; t < 2; ++t)
#pragma unroll
                for (int r = 0; r < 4; ++r) {
                    int colsw = (t * 16 + l15 + (q & 1) * 16) & 31;
                    red[ks * 2048 + (mf * 16 + q4 + r) * 32 + colsw] =
                        acc[mf][p * 2 + t][r];
                }
        __syncthreads();
#pragma unroll
        for (int it = 0; it < 4; ++it) {
            int idx = it * 512 + tid;
            int row = idx >> 5;
            int col = idx & 31;
            int colsw = (col + ((row >> 2) & 1) * 16) & 31;
            float s = 0.f;
#pragma unroll
            for (int w = 0; w < 8; ++w) s += red[w * 2048 + row * 32 + colsw];
            out[(size_t)(b0 + row) * OUT_F + bn * 64 + p * 32 + col] = s;
        }
    }
}

// ===========================================================================
// kan_ablate (DIAGNOSTIC ONLY, writes to d_ws): identical to kan_mfma8
// except the per-j B-loads are hoisted out of the K-loop (B-frags loaded
// once and reused).  Measures m_V1 = phase0 + K-compute + epilogue without
// B-load stalls.  Output is wrong-but-deterministic; real out is untouched.
// ===========================================================================
__global__ __launch_bounds__(512, 4) void kan_ablate(
    const float* __restrict__ x, const char* __restrict__ cp2,
    float* __restrict__ outf) {
    __shared__ uint2 mlds[IN_F][64];

    const int tid = threadIdx.x;
    const int lane = tid & 63;
    const int ks = tid >> 6;
    const int l15 = lane & 15;
    const int q = lane >> 4;
    const int q4 = q * 4;
    const int qc = (q < 3) ? q : 2;

    int wg = (blockIdx.x & 7) * 64 + (blockIdx.x >> 3);
    const int mb = wg >> 2;
    const int bn = wg & 3;
    const int b0 = mb * 64;

    {
        const int row = lane;
        const int jb = ks * 16;
        const float4* xr = reinterpret_cast<const float4*>(
            x + (size_t)(b0 + row) * IN_F + jb);
#pragma unroll
        for (int u = 0; u < 4; ++u) {
            float4 xv = xr[u];
#pragma unroll
            for (int e = 0; e < 4; ++e) {
                float xvv = (e == 0) ? xv.x : (e == 1) ? xv.y
                           : (e == 2) ? xv.z : xv.w;
                float s = 1.0f / (1.0f + __expf(-xvv));
                float idxf = s * 19.0f;
                int k = (int)idxf;
                k = (k > 18) ? 18 : k;
                float w1 = idxf - (float)k;
                float w0 = 1.0f - w1;
                unsigned u0 = __half_as_ushort(__float2half(w0));
                unsigned u1 = __half_as_ushort(__float2half(w1));
                unsigned lo, hi;
                if (k & 1) { lo = u0 << 16; hi = u1; }
                else       { lo = u0 | (u1 << 16); hi = 0u; }
                unsigned P = (unsigned)(k >> 1);
                mlds[jb + u * 4 + e][row] = uint2{lo, hi | (P << 16)};
            }
        }
    }
    __syncthreads();

    const int j0 = ks * JPW;
    const char* bbase = cp2 + (size_t)(bn * 4) * BROW + qc * 256 + l15 * 16;

    f32x4 acc[4][4];
#pragma unroll
    for (int mf = 0; mf < 4; ++mf)
#pragma unroll
        for (int nf = 0; nf < 4; ++nf) acc[mf][nf] = f32x4{0.f, 0.f, 0.f, 0.f};

    // B-frags loaded ONCE (j0 only) — K-loop has no global loads.
    f16x8 rc[4];
#pragma unroll
    for (int h = 0; h < 4; ++h)
        rc[h] = *reinterpret_cast<const f16x8*>(
            bbase + (size_t)(j0 * 16 + h) * BROW);

#pragma unroll 2
    for (int jj = 0; jj < JPW; ++jj) {
        const int j = j0 + jj;
#pragma unroll
        for (int mf = 0; mf < 4; ++mf) {
            uint2 m = mlds[j][mf * 16 + l15];
            unsigned lo = m.x;
            unsigned hi = m.y & 0xFFFFu;
            int d = (int)(m.y >> 16) - q4;
            union { uint32_t u[4]; f16x8 h; } au;
#pragma unroll
            for (int r = 0; r < 4; ++r) {
                uint32_t v = (d == r) ? lo : 0u;
                v = (d == r - 1) ? hi : v;
                au.u[r] = v;
            }
#pragma unroll
            for (int nf = 0; nf < 4; ++nf)
                acc[mf][nf] = __builtin_amdgcn_mfma_f32_16x16x32_f16(
                    au.h, rc[nf], acc[mf][nf], 0, 0, 0);
        }
    }

    __syncthreads();
    float* red = reinterpret_cast<float*>(&mlds[0][0]);
#pragma unroll
    for (int p = 0; p < 2; ++p) {
        if (p) __syncthreads();
#pragma unroll
        for (int mf = 0; mf < 4; ++mf)
#pragma unroll
            for (int t = 0; t < 2; ++t)
#pragma unroll
                for (int r = 0; r < 4; ++r) {
                    int colsw = (t * 16 + l15 + (q & 1) * 16) & 31;
                    red[ks * 2048 + (mf * 16 + q4 + r) * 32 + colsw] =
                        acc[mf][p * 2 + t][r];
                }
        __syncthreads();
#pragma unroll
        for (int it = 0; it < 4; ++it) {
            int idx = it * 512 + tid;
            int row = idx >> 5;
            int col = idx & 31;
            int colsw = (col + ((row >> 2) & 1) * 16) & 31;
            float s = 0.f;
#pragma unroll
            for (int w = 0; w < 8; ++w) s += red[w * 2048 + row * 32 + colsw];
            outf[(size_t)(b0 + row) * OUT_F + bn * 64 + p * 32 + col] = s;
        }
    }
}

// ===========================================================================
// Fallback paths (R2-validated) — used only if d_ws is too small.
// ===========================================================================
__device__ __forceinline__ float dot2_acc(unsigned cbits, unsigned wbits,
                                          float acc) {
#if __has_builtin(__builtin_amdgcn_fdot2)
    union { unsigned u; half2v h; } c, w;
    c.u = cbits; w.u = wbits;
    return __builtin_amdgcn_fdot2(c.h, w.h, acc, false);
#else
    __half2 hc = *reinterpret_cast<const __half2*>(&cbits);
    __half2 hw = *reinterpret_cast<const __half2*>(&wbits);
    float2 fc = __half22float2(hc);
    float2 fw = __half22float2(hw);
    return acc + fc.x * fw.x + fc.y * fw.y;
#endif
}

__global__ __launch_bounds__(256) void build_ctg_kernel(
    const float* __restrict__ coeffs, unsigned short* __restrict__ ctg) {
    int tid = blockIdx.x * 256 + threadIdx.x;
    int qq = tid & 63;
    int k = (tid >> 6) % LC;
    int j = tid / (64 * LC);
    if (j >= IN_F) return;
    int k1 = (k + 1 < LC) ? (k + 1) : (LC - 1);
    union { unsigned short h[8]; uint4 v; } u;
#pragma unroll
    for (int c = 0; c < 4; ++c) {
        int i = qq * 4 + c;
        const float* base = coeffs + ((size_t)i * IN_F + j) * LC;
        u.h[2 * c]     = __half_as_ushort(__float2half(base[k]));
        u.h[2 * c + 1] = __half_as_ushort(__float2half(base[k1]));
    }
    reinterpret_cast<uint4*>(ctg)[tid] = u.v;
}

__global__ __launch_bounds__(256) void kan_main_kernel(
    const float* __restrict__ x, const char* __restrict__ ctg,
    float* __restrict__ out) {
    __shared__ unsigned metas[4][2 * IN_F];
    const int wave = threadIdx.x >> 6;
    const int lane = threadIdx.x & 63;
    const int b = blockIdx.x * 4 + wave;
    float2 xv = reinterpret_cast<const float2*>(x + (size_t)b * IN_F)[lane];
    uint4 m;
#pragma unroll
    for (int t = 0; t < 2; ++t) {
        float xs = t ? xv.y : xv.x;
        float s = 1.0f / (1.0f + __expf(-xs));
        float idxf = s * 19.0f;
        int k = (int)idxf;
        k = (k > 18) ? 18 : k;
        float w1 = idxf - (float)k;
        float w0 = 1.0f - w1;
        int j = 2 * lane + t;
        unsigned off = (unsigned)((j * LC + k) << 10);
        half2v w; w[0] = (_Float16)w0; w[1] = (_Float16)w1;
        unsigned wbits = *reinterpret_cast<unsigned*>(&w);
        if (t == 0) { m.x = off; m.y = wbits; }
        else        { m.z = off; m.w = wbits; }
    }
    reinterpret_cast<uint4*>(&metas[wave][0])[lane] = m;
    __syncthreads();
    const unsigned lanebase = lane * 16;
    const uint4* mrow = reinterpret_cast<const uint4*>(&metas[wave][0]);
    float acc0 = 0.f, acc1 = 0.f, acc2 = 0.f, acc3 = 0.f;
#pragma unroll 8
    for (int j2 = 0; j2 < IN_F / 2; ++j2) {
        uint4 mm = mrow[j2];
        {
            const uint4 e = *reinterpret_cast<const uint4*>(
                ctg + (size_t)(lanebase + mm.x));
            acc0 = dot2_acc(e.x, mm.y, acc0);
            acc1 = dot2_acc(e.y, mm.y, acc1);
            acc2 = dot2_acc(e.z, mm.y, acc2);
            acc3 = dot2_acc(e.w, mm.y, acc3);
        }
        {
            const uint4 e = *reinterpret_cast<const uint4*>(
                ctg + (size_t)(lanebase + mm.z));
            acc0 = dot2_acc(e.x, mm.w, acc0);
            acc1 = dot2_acc(e.y, mm.w, acc1);
            acc2 = dot2_acc(e.z, mm.w, acc2);
            acc3 = dot2_acc(e.w, mm.w, acc3);
        }
    }
    float4 r = make_float4(acc0, acc1, acc2, acc3);
    reinterpret_cast<float4*>(out + (size_t)b * OUT_F)[lane] = r;
}

// ===========================================================================
extern "C" void kernel_launch(void* const* d_in, const int* in_sizes, int n_in,
                              void* d_out, int out_size, void* d_ws,
                              size_t ws_size, hipStream_t stream) {
    const float* x = (const float*)d_in[0];       // [8192, 128] f32
    const float* coeffs = (const float*)d_in[1];  // [256, 128, 23] f32
    float* out = (float*)d_out;                   // [8192, 256] f32

    const size_t cp2_bytes = (size_t)IN_F * 16 * BROW;           // 1.5 MiB
    const size_t ctg_bytes = (size_t)IN_F * LC * 64 * 16;        // ~2.9 MiB
    const size_t abl_off = 2u << 20;                             // 2 MiB
    const size_t abl_bytes = (size_t)BATCH * OUT_F * 4;          // 8 MiB

    if (d_ws != nullptr && ws_size >= cp2_bytes) {
        char* cp2 = (char*)d_ws;
        prep_fast<<<128, 256, 0, stream>>>(coeffs, cp2);
        kan_mfma8<<<512, 512, 0, stream>>>(x, cp2, out);
        // DIAGNOSTIC: no-B-load clone, junk output into d_ws.
        // dur - 30.1 = m_V1 (compute+meta+epilogue without load stalls).
        if (ws_size >= abl_off + abl_bytes) {
            float* wsout = reinterpret_cast<float*>((char*)d_ws + abl_off);
            kan_ablate<<<512, 512, 0, stream>>>(x, cp2, wsout);
        }
    } else if (d_ws != nullptr && ws_size >= ctg_bytes) {
        char* ctg = (char*)d_ws;
        const int totalA = IN_F * LC * 64;
        build_ctg_kernel<<<(totalA + 255) / 256, 256, 0, stream>>>(
            coeffs, (unsigned short*)ctg);
        kan_main_kernel<<<BATCH / 4, 256, 0, stream>>>(x, ctg, out);
    } else {
        kan_main_kernel<<<BATCH / 4, 256, 0, stream>>>(x, (const char*)d_ws,
                                                       out);
    }
}

// Round 15
// 45.719 us; speedup vs baseline: 1.0902x; 1.0902x over previous
//
#include <hip/hip_runtime.h>
#include <hip/hip_fp16.h>

#define BATCH 8192
#define IN_F 128
#define OUT_F 256
#define LC 23        // grid_size + order
#define BROW 768     // bytes per (j,g) cp2 row: 16 cols x 24 slots x 2B

typedef _Float16 f16x8 __attribute__((ext_vector_type(8)));
typedef float f32x4 __attribute__((ext_vector_type(4)));
typedef _Float16 half2v __attribute__((ext_vector_type(2)));

// ===========================================================================
// prep_fast (R13-verified, UNCHANGED): coalesced repack coeffs -> cp2.
// Row (j,g) = [q 3][col 16][16B], slot>=20 -> 0.
// ===========================================================================
__global__ __launch_bounds__(256) void prep_fast(
    const float* __restrict__ coeffs, char* __restrict__ cp2) {
    __shared__ float slab[256 * LC];   // 23552 B
    const size_t base = (size_t)blockIdx.x * 256;
    {
        const float4* g4 = reinterpret_cast<const float4*>(coeffs + base * LC);
        float4* s4 = reinterpret_cast<float4*>(slab);
        for (int it = threadIdx.x; it < (256 * LC) / 4; it += 256)
            s4[it] = g4[it];
    }
    __syncthreads();
    const int t = (int)base + threadIdx.x;
    const int i = t >> 7;
    const int j = t & 127;
    const float* my = slab + threadIdx.x * LC;
    const int g = i >> 4;
    const int col = i & 15;
    char* row = cp2 + (size_t)(j * 16 + g) * BROW + col * 16;
    f16x8 w0, w1, w2;
#pragma unroll
    for (int e = 0; e < 8; ++e) {
        w0[e] = (_Float16)my[e];
        w1[e] = (_Float16)my[8 + e];
        w2[e] = (e < 4) ? (_Float16)my[16 + e] : (_Float16)0.0f;
    }
    *reinterpret_cast<f16x8*>(row) = w0;
    *reinterpret_cast<f16x8*>(row + 256) = w1;
    *reinterpret_cast<f16x8*>(row + 512) = w2;
}

// ===========================================================================
// kan_mfma12: A-fragments materialized in LDS (NO per-j select VALU).
// Block tile: 16 rows x 256 cols (full N) -> meta/phase0 computed ONCE
// (R8 structure recomputed it 4x across bn-blocks).
// Block: 512 thr = 8 waves = 4 bn (col quarter) x 2 ks (j-split).
// Grid = 512 (8192/16 rows); 32 KB LDS -> 2 blocks/CU, 16 waves/CU.
// Per chunk (32 j, x4):
//   zero atab (4 ds_write_b128/thr) -> barrier ->
//   scatter: 1 (j,row) pair/thread: sigmoid -> lo,hi,P; write words P,P+1
//   (fragment row words 11..15 stay zero => q=3 frag reads zeros) -> barrier ->
//   K-loop 16 j/wave: ds_read_b128 A-frag + 4x MFMA (B ping-pong from cp2,
//   qc=min(q,2) trick unchanged) -> barrier.
// Epilogue: 2-way ks reduce via LDS (reuse atab), coalesced stores.
// A-frag semantics IDENTICAL to the R8-verified select path: word W of the
// 16-word row covers pair-slot W; scatter writes lo@P, hi@P+1 (hi=0 if k
// even), so lane (q,l15) reading words 4q..4q+3 gets exactly the verified au.
// ===========================================================================
__global__ __launch_bounds__(512, 4) void kan_mfma12(
    const float* __restrict__ x, const char* __restrict__ cp2,
    float* __restrict__ out) {
    __shared__ unsigned atab[32][16][16];   // 32 KiB: [jj][row][word]

    const int tid = threadIdx.x;
    const int lane = tid & 63;
    const int wv = tid >> 6;
    const int bn = wv & 3;            // col quarter
    const int ks = wv >> 2;           // j-split within chunk
    const int l15 = lane & 15;
    const int q = lane >> 4;
    const int q4 = q * 4;
    const int qc = (q < 3) ? q : 2;   // q=3 B bytes unused (A=0 there)

    const int b0 = blockIdx.x * 16;

    // scatter assignment: row = tid>>5 (16), jj = tid&31 (32) -> x coalesced
    const int s_row = tid >> 5;
    const int s_jj = tid & 31;

    f32x4 acc[4];
#pragma unroll
    for (int nf = 0; nf < 4; ++nf) acc[nf] = f32x4{0.f, 0.f, 0.f, 0.f};

    const char* bbase = cp2 + (size_t)(bn * 4) * BROW + qc * 256 + l15 * 16;

    for (int c = 0; c < 4; ++c) {
        // ---- zero atab ----
        uint4* az = reinterpret_cast<uint4*>(&atab[0][0][0]);
#pragma unroll
        for (int w = 0; w < 4; ++w)
            az[tid + w * 512] = uint4{0u, 0u, 0u, 0u};
        __syncthreads();
        // ---- scatter: one (j,row) pair per thread ----
        {
            const int j = c * 32 + s_jj;
            float xv = x[(size_t)(b0 + s_row) * IN_F + j];
            float s = 1.0f / (1.0f + __expf(-xv));
            float idxf = s * 19.0f;
            int k = (int)idxf;            // floor (idxf >= 0)
            k = (k > 18) ? 18 : k;
            float w1 = idxf - (float)k;
            float w0 = 1.0f - w1;
            unsigned u0 = __half_as_ushort(__float2half(w0));
            unsigned u1 = __half_as_ushort(__float2half(w1));
            unsigned lo, hi;
            if (k & 1) { lo = u0 << 16; hi = u1; }
            else       { lo = u0 | (u1 << 16); hi = 0u; }
            int P = k >> 1;               // <= 9
            atab[s_jj][s_row][P] = lo;
            atab[s_jj][s_row][P + 1] = hi;
        }
        __syncthreads();
        // ---- K-loop: 16 j per wave, B ping-pong ----
        const int jbase = ks * 16;        // within chunk
        auto bldc = [&](int jj2, int nf) {
            return *reinterpret_cast<const f16x8*>(
                bbase + (size_t)((c * 32 + jj2) * 16 + nf) * BROW);
        };
        f16x8 rc[4], rn[4];
#pragma unroll
        for (int h = 0; h < 4; ++h) rc[h] = bldc(jbase, h);
#pragma unroll 2
        for (int jj2 = 0; jj2 < 16; ++jj2) {
            // prefetch next j's B (wraps to jbase at tail: harmless reload)
            const int jnx = jbase + ((jj2 + 1) & 15);
#pragma unroll
            for (int h = 0; h < 4; ++h) rn[h] = bldc(jnx, h);
            union { uint4 v; f16x8 h; } au;
            au.v = *reinterpret_cast<const uint4*>(
                &atab[jbase + jj2][l15][q4]);
#pragma unroll
            for (int nf = 0; nf < 4; ++nf)
                acc[nf] = __builtin_amdgcn_mfma_f32_16x16x32_f16(
                    au.h, rc[nf], acc[nf], 0, 0, 0);
#pragma unroll
            for (int h = 0; h < 4; ++h) rc[h] = rn[h];
        }
        __syncthreads();   // atab reads done before next chunk's zero
    }

    // ---- Epilogue: reduce ks=0/1 partials via LDS (reuse atab) ----
    float* red = reinterpret_cast<float*>(&atab[0][0][0]);   // 8192 f32
    // wv writes its 16x64 partial: C/D layout col=l15, row=q4+r (verified)
#pragma unroll
    for (int nf = 0; nf < 4; ++nf)
#pragma unroll
        for (int r = 0; r < 4; ++r)
            red[wv * 1024 + (q4 + r) * 64 + nf * 16 + l15] = acc[nf][r];
    __syncthreads();
#pragma unroll
    for (int it = 0; it < 8; ++it) {
        int idx = it * 512 + tid;        // [0,4096) = [row 16][col 256]
        int row = idx >> 8;
        int col = idx & 255;
        int cb = col >> 6;               // bn of this col
        int cc = col & 63;
        float s = red[cb * 1024 + row * 64 + cc] +
                  red[(4 + cb) * 1024 + row * 64 + cc];
        out[(size_t)(b0 + row) * OUT_F + col] = s;
    }
}

// ===========================================================================
// Fallback paths (R2-validated) — used only if d_ws is too small.
// ===========================================================================
__device__ __forceinline__ float dot2_acc(unsigned cbits, unsigned wbits,
                                          float acc) {
#if __has_builtin(__builtin_amdgcn_fdot2)
    union { unsigned u; half2v h; } c, w;
    c.u = cbits; w.u = wbits;
    return __builtin_amdgcn_fdot2(c.h, w.h, acc, false);
#else
    __half2 hc = *reinterpret_cast<const __half2*>(&cbits);
    __half2 hw = *reinterpret_cast<const __half2*>(&wbits);
    float2 fc = __half22float2(hc);
    float2 fw = __half22float2(hw);
    return acc + fc.x * fw.x + fc.y * fw.y;
#endif
}

__global__ __launch_bounds__(256) void build_ctg_kernel(
    const float* __restrict__ coeffs, unsigned short* __restrict__ ctg) {
    int tid = blockIdx.x * 256 + threadIdx.x;
    int qq = tid & 63;
    int k = (tid >> 6) % LC;
    int j = tid / (64 * LC);
    if (j >= IN_F) return;
    int k1 = (k + 1 < LC) ? (k + 1) : (LC - 1);
    union { unsigned short h[8]; uint4 v; } u;
#pragma unroll
    for (int c = 0; c < 4; ++c) {
        int i = qq * 4 + c;
        const float* base = coeffs + ((size_t)i * IN_F + j) * LC;
        u.h[2 * c]     = __half_as_ushort(__float2half(base[k]));
        u.h[2 * c + 1] = __half_as_ushort(__float2half(base[k1]));
    }
    reinterpret_cast<uint4*>(ctg)[tid] = u.v;
}

__global__ __launch_bounds__(256) void kan_main_kernel(
    const float* __restrict__ x, const char* __restrict__ ctg,
    float* __restrict__ out) {
    __shared__ unsigned metas[4][2 * IN_F];
    const int wave = threadIdx.x >> 6;
    const int lane = threadIdx.x & 63;
    const int b = blockIdx.x * 4 + wave;
    float2 xv = reinterpret_cast<const float2*>(x + (size_t)b * IN_F)[lane];
    uint4 m;
#pragma unroll
    for (int t = 0; t < 2; ++t) {
        float xs = t ? xv.y : xv.x;
        float s = 1.0f / (1.0f + __expf(-xs));
        float idxf = s * 19.0f;
        int k = (int)idxf;
        k = (k > 18) ? 18 : k;
        float w1 = idxf - (float)k;
        float w0 = 1.0f - w1;
        int j = 2 * lane + t;
        unsigned off = (unsigned)((j * LC + k) << 10);
        half2v w; w[0] = (_Float16)w0; w[1] = (_Float16)w1;
        unsigned wbits = *reinterpret_cast<unsigned*>(&w);
        if (t == 0) { m.x = off; m.y = wbits; }
        else        { m.z = off; m.w = wbits; }
    }
    reinterpret_cast<uint4*>(&metas[wave][0])[lane] = m;
    __syncthreads();
    const unsigned lanebase = lane * 16;
    const uint4* mrow = reinterpret_cast<const uint4*>(&metas[wave][0]);
    float acc0 = 0.f, acc1 = 0.f, acc2 = 0.f, acc3 = 0.f;
#pragma unroll 8
    for (int j2 = 0; j2 < IN_F / 2; ++j2) {
        uint4 mm = mrow[j2];
        {
            const uint4 e = *reinterpret_cast<const uint4*>(
                ctg + (size_t)(lanebase + mm.x));
            acc0 = dot2_acc(e.x, mm.y, acc0);
            acc1 = dot2_acc(e.y, mm.y, acc1);
            acc2 = dot2_acc(e.z, mm.y, acc2);
            acc3 = dot2_acc(e.w, mm.y, acc3);
        }
        {
            const uint4 e = *reinterpret_cast<const uint4*>(
                ctg + (size_t)(lanebase + mm.z));
            acc0 = dot2_acc(e.x, mm.w, acc0);
            acc1 = dot2_acc(e.y, mm.w, acc1);
            acc2 = dot2_acc(e.z, mm.w, acc2);
            acc3 = dot2_acc(e.w, mm.w, acc3);
        }
    }
    float4 r = make_float4(acc0, acc1, acc2, acc3);
    reinterpret_cast<float4*>(out + (size_t)b * OUT_F)[lane] = r;
}

// ===========================================================================
extern "C" void kernel_launch(void* const* d_in, const int* in_sizes, int n_in,
                              void* d_out, int out_size, void* d_ws,
                              size_t ws_size, hipStream_t stream) {
    const float* x = (const float*)d_in[0];       // [8192, 128] f32
    const float* coeffs = (const float*)d_in[1];  // [256, 128, 23] f32
    float* out = (float*)d_out;                   // [8192, 256] f32

    const size_t cp2_bytes = (size_t)IN_F * 16 * BROW;           // 1.5 MiB
    const size_t ctg_bytes = (size_t)IN_F * LC * 64 * 16;        // ~2.9 MiB

    if (d_ws != nullptr && ws_size >= cp2_bytes) {
        char* cp2 = (char*)d_ws;
        prep_fast<<<128, 256, 0, stream>>>(coeffs, cp2);
        kan_mfma12<<<512, 512, 0, stream>>>(x, cp2, out);
    } else if (d_ws != nullptr && ws_size >= ctg_bytes) {
        char* ctg = (char*)d_ws;
        const int totalA = IN_F * LC * 64;
        build_ctg_kernel<<<(totalA + 255) / 256, 256, 0, stream>>>(
            coeffs, (unsigned short*)ctg);
        kan_main_kernel<<<BATCH / 4, 256, 0, stream>>>(x, ctg, out);
    } else {
        kan_main_kernel<<<BATCH / 4, 256, 0, stream>>>(x, (const char*)d_ws,
                                                       out);
    }
}

// Round 16
// 30.929 us; speedup vs baseline: 1.6115x; 1.4782x over previous
//
#include <hip/hip_runtime.h>
#include <hip/hip_fp16.h>

#define BATCH 8192
#define IN_F 128
#define OUT_F 256
#define LC 23        // grid_size + order
#define BROW 768     // bytes per (j,g) cp2 row: 16 cols x 24 slots x 2B
#define JPW 16       // j's per wave (8-way in-block K-split)

typedef _Float16 f16x8 __attribute__((ext_vector_type(8)));
typedef float f32x4 __attribute__((ext_vector_type(4)));
typedef _Float16 half2v __attribute__((ext_vector_type(2)));

// ===========================================================================
// prep_fast (R13-verified): coalesced repack coeffs -> cp2.
// Row (j,g) = [q 3][col 16][16B], slot>=20 -> 0.
// ===========================================================================
__global__ __launch_bounds__(256) void prep_fast(
    const float* __restrict__ coeffs, char* __restrict__ cp2) {
    __shared__ float slab[256 * LC];   // 23552 B
    const size_t base = (size_t)blockIdx.x * 256;   // first (i,j) pair
    {
        const float4* g4 = reinterpret_cast<const float4*>(coeffs + base * LC);
        float4* s4 = reinterpret_cast<float4*>(slab);
        for (int it = threadIdx.x; it < (256 * LC) / 4; it += 256)
            s4[it] = g4[it];
    }
    __syncthreads();
    const int t = (int)base + threadIdx.x;   // pair index = i*128 + j
    const int i = t >> 7;
    const int j = t & 127;
    const float* my = slab + threadIdx.x * LC;
    const int g = i >> 4;
    const int col = i & 15;
    char* row = cp2 + (size_t)(j * 16 + g) * BROW + col * 16;
    f16x8 w0, w1, w2;
#pragma unroll
    for (int e = 0; e < 8; ++e) {
        w0[e] = (_Float16)my[e];
        w1[e] = (_Float16)my[8 + e];
        w2[e] = (e < 4) ? (_Float16)my[16 + e] : (_Float16)0.0f;
    }
    *reinterpret_cast<f16x8*>(row) = w0;          // q0: slots 0-7
    *reinterpret_cast<f16x8*>(row + 256) = w1;    // q1: slots 8-15
    *reinterpret_cast<f16x8*>(row + 512) = w2;    // q2: slots 16-19 (+zeros)
}

// ===========================================================================
// kan_mfma8 (R8/R13-verified champion) + T5 setprio around MFMA cluster.
//   Block: 512 thr = 8 INDEPENDENT waves (no K-loop barriers -> waves are
//   independently phased, the regime where setprio paid on attn, m191).
//   Block tile 64 x 64 (bn in [0,4)); wave computes the full 64x64 partial
//   (mf=4 x nf=4).  Grid = 128 mb x 4 bn = 512 -> 2 blocks/CU, 16 waves/CU.
// Phase 0: meta (sigmoid/bin/weights) -> 64 KiB LDS.
// K-loop: ping-pong B-frag prefetch (2x unrolled); au rebuilt per mf.
//   q=3 lanes re-read q=2 bytes (A-frag there is structurally zero).
// Epilogue: 8-partial reduce in 2 half-passes, XOR-16 swizzle.
// ===========================================================================
__global__ __launch_bounds__(512, 4) void kan_mfma8(
    const float* __restrict__ x, const char* __restrict__ cp2,
    float* __restrict__ out) {
    __shared__ uint2 mlds[IN_F][64];   // 64 KiB: [j][row] meta

    const int tid = threadIdx.x;
    const int lane = tid & 63;
    const int ks = tid >> 6;           // wave id = K-split id [0,8)
    const int l15 = lane & 15;
    const int q = lane >> 4;
    const int q4 = q * 4;
    const int qc = (q < 3) ? q : 2;    // q=3 reads q=2's bytes (A=0 there)

    // bijective XCD swizzle (512 = 8 * 64)
    int wg = (blockIdx.x & 7) * 64 + (blockIdx.x >> 3);
    const int mb = wg >> 2;   // [0,128)
    const int bn = wg & 3;    // [0,4)
    const int b0 = mb * 64;

    // ---- Phase 0: meta for 64 rows x 128 j into LDS ----
    {
        const int row = lane;              // rows 0..63
        const int jb = ks * 16;            // 8 waves x 16 j
        const float4* xr = reinterpret_cast<const float4*>(
            x + (size_t)(b0 + row) * IN_F + jb);
#pragma unroll
        for (int u = 0; u < 4; ++u) {
            float4 xv = xr[u];
#pragma unroll
            for (int e = 0; e < 4; ++e) {
                float xvv = (e == 0) ? xv.x : (e == 1) ? xv.y
                           : (e == 2) ? xv.z : xv.w;
                float s = 1.0f / (1.0f + __expf(-xvv));
                float idxf = s * 19.0f;
                int k = (int)idxf;            // floor (idxf >= 0)
                k = (k > 18) ? 18 : k;
                float w1 = idxf - (float)k;
                float w0 = 1.0f - w1;
                unsigned u0 = __half_as_ushort(__float2half(w0));
                unsigned u1 = __half_as_ushort(__float2half(w1));
                unsigned lo, hi;
                if (k & 1) { lo = u0 << 16; hi = u1; }
                else       { lo = u0 | (u1 << 16); hi = 0u; }
                unsigned P = (unsigned)(k >> 1);
                mlds[jb + u * 4 + e][row] = uint2{lo, hi | (P << 16)};
            }
        }
    }
    __syncthreads();

    // ---- K-loop ----
    const int j0 = ks * JPW;
    const char* bbase = cp2 + (size_t)(bn * 4) * BROW + qc * 256 + l15 * 16;
    auto bld = [&](int j, int nf) {
        return *reinterpret_cast<const f16x8*>(
            bbase + (size_t)(j * 16 + nf) * BROW);
    };

    f32x4 acc[4][4];
#pragma unroll
    for (int mf = 0; mf < 4; ++mf)
#pragma unroll
        for (int nf = 0; nf < 4; ++nf) acc[mf][nf] = f32x4{0.f, 0.f, 0.f, 0.f};

    f16x8 rc[4], rn[4];
#pragma unroll
    for (int h = 0; h < 4; ++h) rc[h] = bld(j0, h);

    auto step = [&](f16x8 (&cur)[4], f16x8 (&nxt)[4], int j, int jn) {
        // prefetch next j's B-frags (land under A-build + MFMA)
#pragma unroll
        for (int h = 0; h < 4; ++h) nxt[h] = bld(jn, h);
#pragma unroll
        for (int mf = 0; mf < 4; ++mf) {
            uint2 m = mlds[j][mf * 16 + l15];
            unsigned lo = m.x;
            unsigned hi = m.y & 0xFFFFu;
            int d = (int)(m.y >> 16) - q4;
            union { uint32_t u[4]; f16x8 h; } au;
#pragma unroll
            for (int r = 0; r < 4; ++r) {
                uint32_t v = (d == r) ? lo : 0u;
                v = (d == r - 1) ? hi : v;
                au.u[r] = v;
            }
            // T5: favor this wave while it drains its MFMA cluster
            __builtin_amdgcn_s_setprio(1);
#pragma unroll
            for (int nf = 0; nf < 4; ++nf)
                acc[mf][nf] = __builtin_amdgcn_mfma_f32_16x16x32_f16(
                    au.h, cur[nf], acc[mf][nf], 0, 0, 0);
            __builtin_amdgcn_s_setprio(0);
        }
    };

    for (int jj = 0; jj < JPW; jj += 2) {
        step(rc, rn, j0 + jj, j0 + jj + 1);
        step(rn, rc, j0 + jj + 1, j0 + ((jj + 2) & (JPW - 1)));  // wrap
    }

    // ---- Epilogue: reduce 8 wave-partials in 2 column-half passes ----
    __syncthreads();   // all waves done reading mlds
    float* red = reinterpret_cast<float*>(&mlds[0][0]);   // 16384 f32
#pragma unroll
    for (int p = 0; p < 2; ++p) {
        if (p) __syncthreads();   // previous pass's reads complete
        // wave ks writes its 64x32 half: C/D layout col=l15, row=q4+r
        // XOR-16 swizzle on col by (q&1): write banks 2-way (free)
#pragma unroll
        for (int mf = 0; mf < 4; ++mf)
#pragma unroll
            for (int t = 0; t < 2; ++t)
#pragma unroll
                for (int r = 0; r < 4; ++r) {
                    int colsw = (t * 16 + l15 + (q & 1) * 16) & 31;
                    red[ks * 2048 + (mf * 16 + q4 + r) * 32 + colsw] =
                        acc[mf][p * 2 + t][r];
                }
        __syncthreads();
#pragma unroll
        for (int it = 0; it < 4; ++it) {
            int idx = it * 512 + tid;   // [0,2048) = [64 rows][32 cols]
            int row = idx >> 5;
            int col = idx & 31;
            int colsw = (col + ((row >> 2) & 1) * 16) & 31;
            float s = 0.f;
#pragma unroll
            for (int w = 0; w < 8; ++w) s += red[w * 2048 + row * 32 + colsw];
            out[(size_t)(b0 + row) * OUT_F + bn * 64 + p * 32 + col] = s;
        }
    }
}

// ===========================================================================
// Fallback paths (R2-validated) — used only if d_ws is too small.
// ===========================================================================
__device__ __forceinline__ float dot2_acc(unsigned cbits, unsigned wbits,
                                          float acc) {
#if __has_builtin(__builtin_amdgcn_fdot2)
    union { unsigned u; half2v h; } c, w;
    c.u = cbits; w.u = wbits;
    return __builtin_amdgcn_fdot2(c.h, w.h, acc, false);
#else
    __half2 hc = *reinterpret_cast<const __half2*>(&cbits);
    __half2 hw = *reinterpret_cast<const __half2*>(&wbits);
    float2 fc = __half22float2(hc);
    float2 fw = __half22float2(hw);
    return acc + fc.x * fw.x + fc.y * fw.y;
#endif
}

__global__ __launch_bounds__(256) void build_ctg_kernel(
    const float* __restrict__ coeffs, unsigned short* __restrict__ ctg) {
    int tid = blockIdx.x * 256 + threadIdx.x;
    int qq = tid & 63;
    int k = (tid >> 6) % LC;
    int j = tid / (64 * LC);
    if (j >= IN_F) return;
    int k1 = (k + 1 < LC) ? (k + 1) : (LC - 1);
    union { unsigned short h[8]; uint4 v; } u;
#pragma unroll
    for (int c = 0; c < 4; ++c) {
        int i = qq * 4 + c;
        const float* base = coeffs + ((size_t)i * IN_F + j) * LC;
        u.h[2 * c]     = __half_as_ushort(__float2half(base[k]));
        u.h[2 * c + 1] = __half_as_ushort(__float2half(base[k1]));
    }
    reinterpret_cast<uint4*>(ctg)[tid] = u.v;
}

__global__ __launch_bounds__(256) void kan_main_kernel(
    const float* __restrict__ x, const char* __restrict__ ctg,
    float* __restrict__ out) {
    __shared__ unsigned metas[4][2 * IN_F];
    const int wave = threadIdx.x >> 6;
    const int lane = threadIdx.x & 63;
    const int b = blockIdx.x * 4 + wave;
    float2 xv = reinterpret_cast<const float2*>(x + (size_t)b * IN_F)[lane];
    uint4 m;
#pragma unroll
    for (int t = 0; t < 2; ++t) {
        float xs = t ? xv.y : xv.x;
        float s = 1.0f / (1.0f + __expf(-xs));
        float idxf = s * 19.0f;
        int k = (int)idxf;
        k = (k > 18) ? 18 : k;
        float w1 = idxf - (float)k;
        float w0 = 1.0f - w1;
        int j = 2 * lane + t;
        unsigned off = (unsigned)((j * LC + k) << 10);
        half2v w; w[0] = (_Float16)w0; w[1] = (_Float16)w1;
        unsigned wbits = *reinterpret_cast<unsigned*>(&w);
        if (t == 0) { m.x = off; m.y = wbits; }
        else        { m.z = off; m.w = wbits; }
    }
    reinterpret_cast<uint4*>(&metas[wave][0])[lane] = m;
    __syncthreads();
    const unsigned lanebase = lane * 16;
    const uint4* mrow = reinterpret_cast<const uint4*>(&metas[wave][0]);
    float acc0 = 0.f, acc1 = 0.f, acc2 = 0.f, acc3 = 0.f;
#pragma unroll 8
    for (int j2 = 0; j2 < IN_F / 2; ++j2) {
        uint4 mm = mrow[j2];
        {
            const uint4 e = *reinterpret_cast<const uint4*>(
                ctg + (size_t)(lanebase + mm.x));
            acc0 = dot2_acc(e.x, mm.y, acc0);
            acc1 = dot2_acc(e.y, mm.y, acc1);
            acc2 = dot2_acc(e.z, mm.y, acc2);
            acc3 = dot2_acc(e.w, mm.y, acc3);
        }
        {
            const uint4 e = *reinterpret_cast<const uint4*>(
                ctg + (size_t)(lanebase + mm.z));
            acc0 = dot2_acc(e.x, mm.w, acc0);
            acc1 = dot2_acc(e.y, mm.w, acc1);
            acc2 = dot2_acc(e.z, mm.w, acc2);
            acc3 = dot2_acc(e.w, mm.w, acc3);
        }
    }
    float4 r = make_float4(acc0, acc1, acc2, acc3);
    reinterpret_cast<float4*>(out + (size_t)b * OUT_F)[lane] = r;
}

// ===========================================================================
extern "C" void kernel_launch(void* const* d_in, const int* in_sizes, int n_in,
                              void* d_out, int out_size, void* d_ws,
                              size_t ws_size, hipStream_t stream) {
    const float* x = (const float*)d_in[0];       // [8192, 128] f32
    const float* coeffs = (const float*)d_in[1];  // [256, 128, 23] f32
    float* out = (float*)d_out;                   // [8192, 256] f32

    const size_t cp2_bytes = (size_t)IN_F * 16 * BROW;           // 1.5 MiB
    const size_t ctg_bytes = (size_t)IN_F * LC * 64 * 16;        // ~2.9 MiB

    if (d_ws != nullptr && ws_size >= cp2_bytes) {
        char* cp2 = (char*)d_ws;
        prep_fast<<<128, 256, 0, stream>>>(coeffs, cp2);
        kan_mfma8<<<512, 512, 0, stream>>>(x, cp2, out);
    } else if (d_ws != nullptr && ws_size >= ctg_bytes) {
        char* ctg = (char*)d_ws;
        const int totalA = IN_F * LC * 64;
        build_ctg_kernel<<<(totalA + 255) / 256, 256, 0, stream>>>(
            coeffs, (unsigned short*)ctg);
        kan_main_kernel<<<BATCH / 4, 256, 0, stream>>>(x, ctg, out);
    } else {
        kan_main_kernel<<<BATCH / 4, 256, 0, stream>>>(x, (const char*)d_ws,
                                                       out);
    }
}

// Round 17
// 30.154 us; speedup vs baseline: 1.6530x; 1.0257x over previous
//
#include <hip/hip_runtime.h>
#include <hip/hip_fp16.h>

#define BATCH 8192
#define IN_F 128
#define OUT_F 256
#define LC 23        // grid_size + order
#define BROW 768     // bytes per (j,g) cp2 row: 16 cols x 24 slots x 2B
#define JPW 16       // j's per wave (8-way in-block K-split)

typedef _Float16 f16x8 __attribute__((ext_vector_type(8)));
typedef float f32x4 __attribute__((ext_vector_type(4)));
typedef _Float16 half2v __attribute__((ext_vector_type(2)));

// ===========================================================================
// prep_fast (R13-verified): coalesced repack coeffs -> cp2.
// Row (j,g) = [q 3][col 16][16B], slot>=20 -> 0.
// ===========================================================================
__global__ __launch_bounds__(256) void prep_fast(
    const float* __restrict__ coeffs, char* __restrict__ cp2) {
    __shared__ float slab[256 * LC];   // 23552 B
    const size_t base = (size_t)blockIdx.x * 256;   // first (i,j) pair
    {
        const float4* g4 = reinterpret_cast<const float4*>(coeffs + base * LC);
        float4* s4 = reinterpret_cast<float4*>(slab);
        for (int it = threadIdx.x; it < (256 * LC) / 4; it += 256)
            s4[it] = g4[it];
    }
    __syncthreads();
    const int t = (int)base + threadIdx.x;   // pair index = i*128 + j
    const int i = t >> 7;
    const int j = t & 127;
    const float* my = slab + threadIdx.x * LC;
    const int g = i >> 4;
    const int col = i & 15;
    char* row = cp2 + (size_t)(j * 16 + g) * BROW + col * 16;
    f16x8 w0, w1, w2;
#pragma unroll
    for (int e = 0; e < 8; ++e) {
        w0[e] = (_Float16)my[e];
        w1[e] = (_Float16)my[8 + e];
        w2[e] = (e < 4) ? (_Float16)my[16 + e] : (_Float16)0.0f;
    }
    *reinterpret_cast<f16x8*>(row) = w0;          // q0: slots 0-7
    *reinterpret_cast<f16x8*>(row + 256) = w1;    // q1: slots 8-15
    *reinterpret_cast<f16x8*>(row + 512) = w2;    // q2: slots 16-19 (+zeros)
}

// ===========================================================================
// kan_mfma8 (R8/R13-verified champion, setprio removed — measured null):
// out = W * C via mfma_f32_16x16x32_f16.
//   Block: 512 thr = 8 INDEPENDENT waves; wave ks owns j in [ks*16,ks*16+16).
//   Block tile 64 x 64 (bn in [0,4)); wave computes the full 64x64 partial
//   (mf=4 x nf=4).  Grid = 128 mb x 4 bn = 512 -> 2 blocks/CU, 16 waves/CU.
// Regime note (R14 ablation + R7/R8/R10/R16 nulls): SIMD issue-slot bound —
// MFMA ~8.3us/CU (padded K=4096) + A-build VALU ~4us share issue slots;
// latency knobs (occupancy, prefetch depth, setprio) are correctly null.
// Phase 0: meta (sigmoid/bin/weights) -> 64 KiB LDS.
// K-loop: ping-pong B-frag prefetch (2x unrolled); au rebuilt per mf.
//   q=3 lanes re-read q=2 bytes (A-frag there is structurally zero).
// Epilogue: 8-partial reduce in 2 half-passes, XOR-16 swizzle.
// ===========================================================================
__global__ __launch_bounds__(512, 4) void kan_mfma8(
    const float* __restrict__ x, const char* __restrict__ cp2,
    float* __restrict__ out) {
    __shared__ uint2 mlds[IN_F][64];   // 64 KiB: [j][row] meta

    const int tid = threadIdx.x;
    const int lane = tid & 63;
    const int ks = tid >> 6;           // wave id = K-split id [0,8)
    const int l15 = lane & 15;
    const int q = lane >> 4;
    const int q4 = q * 4;
    const int qc = (q < 3) ? q : 2;    // q=3 reads q=2's bytes (A=0 there)

    // bijective XCD swizzle (512 = 8 * 64)
    int wg = (blockIdx.x & 7) * 64 + (blockIdx.x >> 3);
    const int mb = wg >> 2;   // [0,128)
    const int bn = wg & 3;    // [0,4)
    const int b0 = mb * 64;

    // ---- Phase 0: meta for 64 rows x 128 j into LDS ----
    {
        const int row = lane;              // rows 0..63
        const int jb = ks * 16;            // 8 waves x 16 j
        const float4* xr = reinterpret_cast<const float4*>(
            x + (size_t)(b0 + row) * IN_F + jb);
#pragma unroll
        for (int u = 0; u < 4; ++u) {
            float4 xv = xr[u];
#pragma unroll
            for (int e = 0; e < 4; ++e) {
                float xvv = (e == 0) ? xv.x : (e == 1) ? xv.y
                           : (e == 2) ? xv.z : xv.w;
                float s = 1.0f / (1.0f + __expf(-xvv));
                float idxf = s * 19.0f;
                int k = (int)idxf;            // floor (idxf >= 0)
                k = (k > 18) ? 18 : k;
                float w1 = idxf - (float)k;
                float w0 = 1.0f - w1;
                unsigned u0 = __half_as_ushort(__float2half(w0));
                unsigned u1 = __half_as_ushort(__float2half(w1));
                unsigned lo, hi;
                if (k & 1) { lo = u0 << 16; hi = u1; }
                else       { lo = u0 | (u1 << 16); hi = 0u; }
                unsigned P = (unsigned)(k >> 1);
                mlds[jb + u * 4 + e][row] = uint2{lo, hi | (P << 16)};
            }
        }
    }
    __syncthreads();

    // ---- K-loop ----
    const int j0 = ks * JPW;
    const char* bbase = cp2 + (size_t)(bn * 4) * BROW + qc * 256 + l15 * 16;
    auto bld = [&](int j, int nf) {
        return *reinterpret_cast<const f16x8*>(
            bbase + (size_t)(j * 16 + nf) * BROW);
    };

    f32x4 acc[4][4];
#pragma unroll
    for (int mf = 0; mf < 4; ++mf)
#pragma unroll
        for (int nf = 0; nf < 4; ++nf) acc[mf][nf] = f32x4{0.f, 0.f, 0.f, 0.f};

    f16x8 rc[4], rn[4];
#pragma unroll
    for (int h = 0; h < 4; ++h) rc[h] = bld(j0, h);

    auto step = [&](f16x8 (&cur)[4], f16x8 (&nxt)[4], int j, int jn) {
        // prefetch next j's B-frags (land under A-build + MFMA)
#pragma unroll
        for (int h = 0; h < 4; ++h) nxt[h] = bld(jn, h);
#pragma unroll
        for (int mf = 0; mf < 4; ++mf) {
            uint2 m = mlds[j][mf * 16 + l15];
            unsigned lo = m.x;
            unsigned hi = m.y & 0xFFFFu;
            int d = (int)(m.y >> 16) - q4;
            union { uint32_t u[4]; f16x8 h; } au;
#pragma unroll
            for (int r = 0; r < 4; ++r) {
                uint32_t v = (d == r) ? lo : 0u;
                v = (d == r - 1) ? hi : v;
                au.u[r] = v;
            }
#pragma unroll
            for (int nf = 0; nf < 4; ++nf)
                acc[mf][nf] = __builtin_amdgcn_mfma_f32_16x16x32_f16(
                    au.h, cur[nf], acc[mf][nf], 0, 0, 0);
        }
    };

    for (int jj = 0; jj < JPW; jj += 2) {
        step(rc, rn, j0 + jj, j0 + jj + 1);
        step(rn, rc, j0 + jj + 1, j0 + ((jj + 2) & (JPW - 1)));  // wrap
    }

    // ---- Epilogue: reduce 8 wave-partials in 2 column-half passes ----
    __syncthreads();   // all waves done reading mlds
    float* red = reinterpret_cast<float*>(&mlds[0][0]);   // 16384 f32
#pragma unroll
    for (int p = 0; p < 2; ++p) {
        if (p) __syncthreads();   // previous pass's reads complete
        // wave ks writes its 64x32 half: C/D layout col=l15, row=q4+r
        // XOR-16 swizzle on col by (q&1): write banks 2-way (free)
#pragma unroll
        for (int mf = 0; mf < 4; ++mf)
#pragma unroll
            for (int t = 0; t < 2; ++t)
#pragma unroll
                for (int r = 0; r < 4; ++r) {
                    int colsw = (t * 16 + l15 + (q & 1) * 16) & 31;
                    red[ks * 2048 + (mf * 16 + q4 + r) * 32 + colsw] =
                        acc[mf][p * 2 + t][r];
                }
        __syncthreads();
#pragma unroll
        for (int it = 0; it < 4; ++it) {
            int idx = it * 512 + tid;   // [0,2048) = [64 rows][32 cols]
            int row = idx >> 5;
            int col = idx & 31;
            int colsw = (col + ((row >> 2) & 1) * 16) & 31;
            float s = 0.f;
#pragma unroll
            for (int w = 0; w < 8; ++w) s += red[w * 2048 + row * 32 + colsw];
            out[(size_t)(b0 + row) * OUT_F + bn * 64 + p * 32 + col] = s;
        }
    }
}

// ===========================================================================
// Fallback paths (R2-validated) — used only if d_ws is too small.
// ===========================================================================
__device__ __forceinline__ float dot2_acc(unsigned cbits, unsigned wbits,
                                          float acc) {
#if __has_builtin(__builtin_amdgcn_fdot2)
    union { unsigned u; half2v h; } c, w;
    c.u = cbits; w.u = wbits;
    return __builtin_amdgcn_fdot2(c.h, w.h, acc, false);
#else
    __half2 hc = *reinterpret_cast<const __half2*>(&cbits);
    __half2 hw = *reinterpret_cast<const __half2*>(&wbits);
    float2 fc = __half22float2(hc);
    float2 fw = __half22float2(hw);
    return acc + fc.x * fw.x + fc.y * fw.y;
#endif
}

__global__ __launch_bounds__(256) void build_ctg_kernel(
    const float* __restrict__ coeffs, unsigned short* __restrict__ ctg) {
    int tid = blockIdx.x * 256 + threadIdx.x;
    int qq = tid & 63;
    int k = (tid >> 6) % LC;
    int j = tid / (64 * LC);
    if (j >= IN_F) return;
    int k1 = (k + 1 < LC) ? (k + 1) : (LC - 1);
    union { unsigned short h[8]; uint4 v; } u;
#pragma unroll
    for (int c = 0; c < 4; ++c) {
        int i = qq * 4 + c;
        const float* base = coeffs + ((size_t)i * IN_F + j) * LC;
        u.h[2 * c]     = __half_as_ushort(__float2half(base[k]));
        u.h[2 * c + 1] = __half_as_ushort(__float2half(base[k1]));
    }
    reinterpret_cast<uint4*>(ctg)[tid] = u.v;
}

__global__ __launch_bounds__(256) void kan_main_kernel(
    const float* __restrict__ x, const char* __restrict__ ctg,
    float* __restrict__ out) {
    __shared__ unsigned metas[4][2 * IN_F];
    const int wave = threadIdx.x >> 6;
    const int lane = threadIdx.x & 63;
    const int b = blockIdx.x * 4 + wave;
    float2 xv = reinterpret_cast<const float2*>(x + (size_t)b * IN_F)[lane];
    uint4 m;
#pragma unroll
    for (int t = 0; t < 2; ++t) {
        float xs = t ? xv.y : xv.x;
        float s = 1.0f / (1.0f + __expf(-xs));
        float idxf = s * 19.0f;
        int k = (int)idxf;
        k = (k > 18) ? 18 : k;
        float w1 = idxf - (float)k;
        float w0 = 1.0f - w1;
        int j = 2 * lane + t;
        unsigned off = (unsigned)((j * LC + k) << 10);
        half2v w; w[0] = (_Float16)w0; w[1] = (_Float16)w1;
        unsigned wbits = *reinterpret_cast<unsigned*>(&w);
        if (t == 0) { m.x = off; m.y = wbits; }
        else        { m.z = off; m.w = wbits; }
    }
    reinterpret_cast<uint4*>(&metas[wave][0])[lane] = m;
    __syncthreads();
    const unsigned lanebase = lane * 16;
    const uint4* mrow = reinterpret_cast<const uint4*>(&metas[wave][0]);
    float acc0 = 0.f, acc1 = 0.f, acc2 = 0.f, acc3 = 0.f;
#pragma unroll 8
    for (int j2 = 0; j2 < IN_F / 2; ++j2) {
        uint4 mm = mrow[j2];
        {
            const uint4 e = *reinterpret_cast<const uint4*>(
                ctg + (size_t)(lanebase + mm.x));
            acc0 = dot2_acc(e.x, mm.y, acc0);
            acc1 = dot2_acc(e.y, mm.y, acc1);
            acc2 = dot2_acc(e.z, mm.y, acc2);
            acc3 = dot2_acc(e.w, mm.y, acc3);
        }
        {
            const uint4 e = *reinterpret_cast<const uint4*>(
                ctg + (size_t)(lanebase + mm.z));
            acc0 = dot2_acc(e.x, mm.w, acc0);
            acc1 = dot2_acc(e.y, mm.w, acc1);
            acc2 = dot2_acc(e.z, mm.w, acc2);
            acc3 = dot2_acc(e.w, mm.w, acc3);
        }
    }
    float4 r = make_float4(acc0, acc1, acc2, acc3);
    reinterpret_cast<float4*>(out + (size_t)b * OUT_F)[lane] = r;
}

// ===========================================================================
extern "C" void kernel_launch(void* const* d_in, const int* in_sizes, int n_in,
                              void* d_out, int out_size, void* d_ws,
                              size_t ws_size, hipStream_t stream) {
    const float* x = (const float*)d_in[0];       // [8192, 128] f32
    const float* coeffs = (const float*)d_in[1];  // [256, 128, 23] f32
    float* out = (float*)d_out;                   // [8192, 256] f32

    const size_t cp2_bytes = (size_t)IN_F * 16 * BROW;           // 1.5 MiB
    const size_t ctg_bytes = (size_t)IN_F * LC * 64 * 16;        // ~2.9 MiB

    if (d_ws != nullptr && ws_size >= cp2_bytes) {
        char* cp2 = (char*)d_ws;
        prep_fast<<<128, 256, 0, stream>>>(coeffs, cp2);
        kan_mfma8<<<512, 512, 0, stream>>>(x, cp2, out);
    } else if (d_ws != nullptr && ws_size >= ctg_bytes) {
        char* ctg = (char*)d_ws;
        const int totalA = IN_F * LC * 64;
        build_ctg_kernel<<<(totalA + 255) / 256, 256, 0, stream>>>(
            coeffs, (unsigned short*)ctg);
        kan_main_kernel<<<BATCH / 4, 256, 0, stream>>>(x, ctg, out);
    } else {
        kan_main_kernel<<<BATCH / 4, 256, 0, stream>>>(x, (const char*)d_ws,
                                                       out);
    }
}